// Round 1
// baseline (762.410 us; speedup 1.0000x reference)
//
#include <hip/hip_runtime.h>
#include <math.h>

#define NPTS  131072
#define FEAT  64
#define KCLUS 2048
#define CHUNK 128
#define BLOCK 256

// ---------------------------------------------------------------------------
// cnorm[k] = ||c_k||^2
// ---------------------------------------------------------------------------
__global__ void cnorm_kernel(const float* __restrict__ c, float* __restrict__ cnorm) {
    int k = blockIdx.x * blockDim.x + threadIdx.x;
    if (k < KCLUS) {
        const float4* row = (const float4*)&c[k * FEAT];
        float s = 0.f;
#pragma unroll
        for (int j = 0; j < FEAT / 4; ++j) {
            float4 v = row[j];
            s = fmaf(v.x, v.x, s);
            s = fmaf(v.y, v.y, s);
            s = fmaf(v.z, v.z, s);
            s = fmaf(v.w, v.w, s);
        }
        cnorm[k] = s;
    }
}

// ---------------------------------------------------------------------------
// Per point: argmin_k ( ||c_k||^2 - 2 x.c_k )   (||x||^2 constant per point)
// Then fused scatter: sums[k][:] += x, counts[k] += 1 (wave-transposed, one
// coalesced 256B atomic row per point).
// ---------------------------------------------------------------------------
__global__ void assign_scatter_kernel(const float* __restrict__ x,
                                      const float* __restrict__ c,
                                      const float* __restrict__ cnorm,
                                      float* __restrict__ out_assign,
                                      float* __restrict__ sums,
                                      int* __restrict__ counts) {
    __shared__ float cs[CHUNK * FEAT];   // 32 KB centroid chunk
    __shared__ float cn[CHUNK];          // chunk norms
    __shared__ int   asg[BLOCK];         // per-point argmin for scatter phase

    const int pt = blockIdx.x * BLOCK + threadIdx.x;

    // Point's 64 features in VGPRs.
    float xr[FEAT];
#pragma unroll
    for (int j = 0; j < FEAT; j += 4) {
        float4 v = *(const float4*)&x[pt * FEAT + j];
        xr[j] = v.x; xr[j + 1] = v.y; xr[j + 2] = v.z; xr[j + 3] = v.w;
    }

    float bestd = INFINITY;
    int   bestk = 0;

    for (int k0 = 0; k0 < KCLUS; k0 += CHUNK) {
        __syncthreads();
        // Stage CHUNK centroids: 8192 floats = 2048 float4, 8 per thread, coalesced.
#pragma unroll
        for (int t = 0; t < (CHUNK * FEAT) / (BLOCK * 4); ++t) {
            int f4 = t * BLOCK + threadIdx.x;
            *(float4*)&cs[f4 * 4] = *(const float4*)&c[k0 * FEAT + f4 * 4];
        }
        if (threadIdx.x < CHUNK) cn[threadIdx.x] = cnorm[k0 + threadIdx.x];
        __syncthreads();

#pragma unroll 1
        for (int cc = 0; cc < CHUNK; cc += 4) {
            float a0 = 0.f, a1 = 0.f, a2 = 0.f, a3 = 0.f;
#pragma unroll
            for (int j = 0; j < FEAT; j += 4) {
                float4 c0 = *(const float4*)&cs[(cc + 0) * FEAT + j];
                float4 c1 = *(const float4*)&cs[(cc + 1) * FEAT + j];
                float4 c2 = *(const float4*)&cs[(cc + 2) * FEAT + j];
                float4 c3 = *(const float4*)&cs[(cc + 3) * FEAT + j];
                a0 = fmaf(xr[j], c0.x, a0); a0 = fmaf(xr[j + 1], c0.y, a0);
                a0 = fmaf(xr[j + 2], c0.z, a0); a0 = fmaf(xr[j + 3], c0.w, a0);
                a1 = fmaf(xr[j], c1.x, a1); a1 = fmaf(xr[j + 1], c1.y, a1);
                a1 = fmaf(xr[j + 2], c1.z, a1); a1 = fmaf(xr[j + 3], c1.w, a1);
                a2 = fmaf(xr[j], c2.x, a2); a2 = fmaf(xr[j + 1], c2.y, a2);
                a2 = fmaf(xr[j + 2], c2.z, a2); a2 = fmaf(xr[j + 3], c2.w, a2);
                a3 = fmaf(xr[j], c3.x, a3); a3 = fmaf(xr[j + 1], c3.y, a3);
                a3 = fmaf(xr[j + 2], c3.z, a3); a3 = fmaf(xr[j + 3], c3.w, a3);
            }
            float d0 = fmaf(-2.f, a0, cn[cc + 0]);
            float d1 = fmaf(-2.f, a1, cn[cc + 1]);
            float d2 = fmaf(-2.f, a2, cn[cc + 2]);
            float d3 = fmaf(-2.f, a3, cn[cc + 3]);
            // Ascending k + strict < keeps the first (lowest) index on ties,
            // matching argmin semantics.
            if (d0 < bestd) { bestd = d0; bestk = k0 + cc + 0; }
            if (d1 < bestd) { bestd = d1; bestk = k0 + cc + 1; }
            if (d2 < bestd) { bestd = d2; bestk = k0 + cc + 2; }
            if (d3 < bestd) { bestd = d3; bestk = k0 + cc + 3; }
        }
    }

    out_assign[pt] = (float)bestk;   // d_out is float; indices exact to 2^24
    asg[threadIdx.x] = bestk;
    __syncthreads();

    // Wave-transposed scatter: lane = feature, iterate the wave's 64 points.
    const int lane  = threadIdx.x & 63;
    const int wv    = threadIdx.x >> 6;
    const int pbase = blockIdx.x * BLOCK + wv * 64;
#pragma unroll 1
    for (int p = 0; p < 64; ++p) {
        int   a  = asg[wv * 64 + p];                 // LDS broadcast
        float xv = x[(pbase + p) * FEAT + lane];     // coalesced 256B row
        atomicAdd(&sums[a * FEAT + lane], xv);       // coalesced 256B atomic row
        if (lane == 0) atomicAdd(&counts[a], 1);
    }
}

// ---------------------------------------------------------------------------
// updated = 0.99*c + 0.01*(counts>0 ? sums/counts : c)
// ---------------------------------------------------------------------------
__global__ void update_kernel(const float* __restrict__ c,
                              const float* __restrict__ sums,
                              const int* __restrict__ counts,
                              float* __restrict__ out_upd) {
    int i = blockIdx.x * blockDim.x + threadIdx.x;
    if (i < KCLUS * FEAT) {
        int   k   = i >> 6;
        float cv  = c[i];
        int   cnt = counts[k];
        float nc  = (cnt > 0) ? (sums[i] / (float)cnt) : cv;
        out_upd[i] = 0.99f * cv + 0.01f * nc;
    }
}

extern "C" void kernel_launch(void* const* d_in, const int* in_sizes, int n_in,
                              void* d_out, int out_size, void* d_ws, size_t ws_size,
                              hipStream_t stream) {
    const float* x = (const float*)d_in[0];
    const float* c = (const float*)d_in[1];

    float* out        = (float*)d_out;
    float* out_assign = out;           // [0, N): assignments as float
    float* out_upd    = out + NPTS;    // [N, N + K*FEAT): updated centroids

    char*  ws     = (char*)d_ws;
    float* cnorm  = (float*)ws;                                  // 8 KB
    float* sums   = (float*)(ws + 8192);                         // 512 KB
    int*   counts = (int*)(ws + 8192 + (size_t)KCLUS * FEAT * 4); // 8 KB

    // sums + counts are contiguous — single async memset (graph-capture safe).
    hipMemsetAsync(sums, 0, (size_t)KCLUS * FEAT * 4 + KCLUS * 4, stream);

    cnorm_kernel<<<KCLUS / 256, 256, 0, stream>>>(c, cnorm);
    assign_scatter_kernel<<<NPTS / BLOCK, BLOCK, 0, stream>>>(x, c, cnorm,
                                                              out_assign, sums, counts);
    update_kernel<<<(KCLUS * FEAT) / 256, 256, 0, stream>>>(c, sums, counts, out_upd);
}

// Round 2
// 538.044 us; speedup vs baseline: 1.4170x; 1.4170x over previous
//
#include <hip/hip_runtime.h>
#include <math.h>

#define NPTS   131072
#define FEAT   64
#define KCLUS  2048
#define CHUNKC 256      // clusters staged per LDS chunk
#define CROW   72       // padded LDS row stride in shorts (64 + 8): 2-way banks = free

typedef __attribute__((ext_vector_type(8))) short frag_ab;   // 8 bf16 (4 VGPRs)
typedef __attribute__((ext_vector_type(4))) float frag_cd;   // 4 fp32 acc

// fp32 -> bf16, round-to-nearest-even (bit-exact, no reliance on compiler cvt mode)
__device__ __forceinline__ short f2bf(float f) {
    unsigned u = __float_as_uint(f);
    u += 0x7FFFu + ((u >> 16) & 1u);
    return (short)(u >> 16);
}

// ---------------------------------------------------------------------------
// Per cluster: exact fp32 ||c||^2 (same FMA order as round 1 -> same argmin
// arithmetic), bf16 copy of the row, and atomicMax of ||c|| into cmax.
// ---------------------------------------------------------------------------
__global__ void cprep_kernel(const float* __restrict__ c,
                             float* __restrict__ cnorm,
                             short* __restrict__ cbs,
                             float* __restrict__ cmax) {
    int k = blockIdx.x * blockDim.x + threadIdx.x;
    if (k >= KCLUS) return;
    const float4* row = (const float4*)&c[k * FEAT];
    float s = 0.f;
#pragma unroll
    for (int j = 0; j < 16; ++j) {
        float4 v = row[j];
        s = fmaf(v.x, v.x, s); s = fmaf(v.y, v.y, s);
        s = fmaf(v.z, v.z, s); s = fmaf(v.w, v.w, s);
        short4 b;
        b.x = f2bf(v.x); b.y = f2bf(v.y); b.z = f2bf(v.z); b.w = f2bf(v.w);
        *(short4*)&cbs[k * FEAT + j * 4] = b;
    }
    cnorm[k] = s;
    atomicMax((int*)cmax, __float_as_int(sqrtf(s)));  // positive floats: int-max == float-max
}

// Per point: ||x|| for the error bound
__global__ void xprep_kernel(const float* __restrict__ x, float* __restrict__ xn) {
    int p = blockIdx.x * blockDim.x + threadIdx.x;
    const float4* row = (const float4*)&x[(size_t)p * FEAT];
    float s = 0.f;
#pragma unroll
    for (int j = 0; j < 16; ++j) {
        float4 v = row[j];
        s = fmaf(v.x, v.x, s); s = fmaf(v.y, v.y, s);
        s = fmaf(v.z, v.z, s); s = fmaf(v.w, v.w, s);
    }
    xn[p] = sqrtf(s);
}

// ---------------------------------------------------------------------------
// MFMA assign: pass 1 -> approx min per point; pass 2 -> exact fp32 refine of
// all clusters within the rigorous bf16 error margin. Wave = 64 points
// (4 row-tiles of 16), cluster chunks of 256 staged in LDS.
// ---------------------------------------------------------------------------
__global__ __launch_bounds__(256) void assign_kernel(
    const float* __restrict__ x, const float* __restrict__ c,
    const short* __restrict__ cbs, const float* __restrict__ cnorm,
    const float* __restrict__ xn, const float* __restrict__ cmaxp,
    float* __restrict__ out_assign)
{
    __shared__ short csh[CHUNKC * CROW];
    __shared__ float cnsh[CHUNKC];

    const int tid  = threadIdx.x;
    const int wv   = tid >> 6;
    const int lane = tid & 63;
    const int col  = lane & 15;   // MFMA col / A-row index
    const int q    = lane >> 4;   // quad
    const int pt0  = blockIdx.x * 256 + wv * 64;

    // A-frags: lane holds A[m=lane&15][k=q*8+j] (m120-verified layout);
    // converted fp32->bf16 once, reused for all 2048 clusters, both passes.
    frag_ab A[4][2];
#pragma unroll
    for (int rt = 0; rt < 4; ++rt)
#pragma unroll
        for (int kh = 0; kh < 2; ++kh) {
            const float4* xp = (const float4*)&x[(size_t)(pt0 + rt * 16 + col) * FEAT + kh * 32 + q * 8];
            float4 v0 = xp[0], v1 = xp[1];
            frag_ab a;
            a[0] = f2bf(v0.x); a[1] = f2bf(v0.y); a[2] = f2bf(v0.z); a[3] = f2bf(v0.w);
            a[4] = f2bf(v1.x); a[5] = f2bf(v1.y); a[6] = f2bf(v1.z); a[7] = f2bf(v1.w);
            A[rt][kh] = a;
        }

    const float cmax = *cmaxp;

    float m[4][4];
#pragma unroll
    for (int rt = 0; rt < 4; ++rt)
#pragma unroll
        for (int r = 0; r < 4; ++r) m[rt][r] = INFINITY;

    // ---------------- PASS 1: approx min only (1 fma + 1 min per value) ----
    for (int k0 = 0; k0 < KCLUS; k0 += CHUNKC) {
        __syncthreads();
#pragma unroll
        for (int i = 0; i < 8; ++i) {           // 32KB chunk, coalesced 16B/thread
            int f = i * 256 + tid;
            int lc = f >> 3, part = f & 7;
            *(frag_ab*)&csh[lc * CROW + part * 8] =
                *(const frag_ab*)&cbs[(size_t)(k0 + lc) * FEAT + part * 8];
        }
        cnsh[tid] = cnorm[k0 + tid];
        __syncthreads();

#pragma unroll 1
        for (int ct = 0; ct < CHUNKC / 16; ++ct) {
            const int lc = ct * 16 + col;
            frag_ab b0 = *(const frag_ab*)&csh[lc * CROW + q * 8];
            frag_ab b1 = *(const frag_ab*)&csh[lc * CROW + 32 + q * 8];
            const float cnv = cnsh[lc];
#pragma unroll
            for (int rt = 0; rt < 4; ++rt) {
                frag_cd acc = {0.f, 0.f, 0.f, 0.f};
                acc = __builtin_amdgcn_mfma_f32_16x16x32_bf16(A[rt][0], b0, acc, 0, 0, 0);
                acc = __builtin_amdgcn_mfma_f32_16x16x32_bf16(A[rt][1], b1, acc, 0, 0, 0);
#pragma unroll
                for (int r = 0; r < 4; ++r) {
                    float d = fmaf(-2.f, acc[r], cnv);
                    m[rt][r] = fminf(m[rt][r], d);
                }
            }
        }
    }

    // Cross-lane min over the 16 col-classes; threshold with rigorous margin:
    // |d~ - d| <= 2 * 1.01 * 2^-7 * ||x||*||c||  ->  2*eps <= 0.0316*xn*cmax < 0.034
    float t[4][4];
#pragma unroll
    for (int rt = 0; rt < 4; ++rt)
#pragma unroll
        for (int r = 0; r < 4; ++r) {
            float mm = m[rt][r];
            mm = fminf(mm, __shfl_xor(mm, 1));
            mm = fminf(mm, __shfl_xor(mm, 2));
            mm = fminf(mm, __shfl_xor(mm, 4));
            mm = fminf(mm, __shfl_xor(mm, 8));
            t[rt][r] = mm + xn[pt0 + rt * 16 + q * 4 + r] * cmax * 0.034f;
        }

    float bestd[4][4];
    int   bestk[4][4];
#pragma unroll
    for (int rt = 0; rt < 4; ++rt)
#pragma unroll
        for (int r = 0; r < 4; ++r) { bestd[rt][r] = INFINITY; bestk[rt][r] = 0x7fffffff; }

    // ---------------- PASS 2: candidates -> exact fp32 recompute -----------
    for (int k0 = 0; k0 < KCLUS; k0 += CHUNKC) {
        __syncthreads();
#pragma unroll
        for (int i = 0; i < 8; ++i) {
            int f = i * 256 + tid;
            int lc = f >> 3, part = f & 7;
            *(frag_ab*)&csh[lc * CROW + part * 8] =
                *(const frag_ab*)&cbs[(size_t)(k0 + lc) * FEAT + part * 8];
        }
        cnsh[tid] = cnorm[k0 + tid];
        __syncthreads();

#pragma unroll 1
        for (int ct = 0; ct < CHUNKC / 16; ++ct) {
            const int lc = ct * 16 + col;
            frag_ab b0 = *(const frag_ab*)&csh[lc * CROW + q * 8];
            frag_ab b1 = *(const frag_ab*)&csh[lc * CROW + 32 + q * 8];
            const float cnv = cnsh[lc];
#pragma unroll
            for (int rt = 0; rt < 4; ++rt) {
                frag_cd acc = {0.f, 0.f, 0.f, 0.f};
                acc = __builtin_amdgcn_mfma_f32_16x16x32_bf16(A[rt][0], b0, acc, 0, 0, 0);
                acc = __builtin_amdgcn_mfma_f32_16x16x32_bf16(A[rt][1], b1, acc, 0, 0, 0);
#pragma unroll
                for (int r = 0; r < 4; ++r) {
                    float d = fmaf(-2.f, acc[r], cnv);
                    if (d <= t[rt][r]) {     // rare (~1-2 per point over both loops)
                        const int kk = k0 + lc;
                        const int p  = pt0 + rt * 16 + q * 4 + r;
                        const float4* xr4 = (const float4*)&x[(size_t)p * FEAT];
                        const float4* cr4 = (const float4*)&c[(size_t)kk * FEAT];
                        float s = 0.f;
#pragma unroll
                        for (int j = 0; j < 16; ++j) {   // same order as round-1 exact path
                            float4 a4 = xr4[j], b4 = cr4[j];
                            s = fmaf(a4.x, b4.x, s); s = fmaf(a4.y, b4.y, s);
                            s = fmaf(a4.z, b4.z, s); s = fmaf(a4.w, b4.w, s);
                        }
                        float de = fmaf(-2.f, s, cnv);
                        if (de < bestd[rt][r] || (de == bestd[rt][r] && kk < bestk[rt][r])) {
                            bestd[rt][r] = de; bestk[rt][r] = kk;
                        }
                    }
                }
            }
        }
    }

    // Cross-lane (d,k) min with min-k tie-break == reference argmin semantics.
#pragma unroll
    for (int rt = 0; rt < 4; ++rt) {
#pragma unroll
        for (int r = 0; r < 4; ++r) {
            float bd = bestd[rt][r]; int bk = bestk[rt][r];
#pragma unroll
            for (int mask = 1; mask <= 8; mask <<= 1) {
                float od = __shfl_xor(bd, mask);
                int   ok = __shfl_xor(bk, mask);
                if (od < bd || (od == bd && ok < bk)) { bd = od; bk = ok; }
            }
            bestd[rt][r] = bd; bestk[rt][r] = bk;
        }
        if (col == 0) {
            float4 w = { (float)bestk[rt][0], (float)bestk[rt][1],
                         (float)bestk[rt][2], (float)bestk[rt][3] };
            *(float4*)&out_assign[pt0 + rt * 16 + q * 4] = w;
        }
    }
}

// ---------------------------------------------------------------------------
// Wave-transposed scatter: lane = feature, one coalesced 256B atomic row/point
// ---------------------------------------------------------------------------
__global__ void scatter_kernel(const float* __restrict__ x,
                               const float* __restrict__ assign_f,
                               float* __restrict__ sums, int* __restrict__ counts) {
    const int lane  = threadIdx.x & 63;
    const int wv    = threadIdx.x >> 6;
    const int pbase = blockIdx.x * 256 + wv * 64;
#pragma unroll 1
    for (int p = 0; p < 64; ++p) {
        int   a  = (int)assign_f[pbase + p];
        float xv = x[(size_t)(pbase + p) * FEAT + lane];
        atomicAdd(&sums[a * FEAT + lane], xv);
        if (lane == 0) atomicAdd(&counts[a], 1);
    }
}

__global__ void update_kernel(const float* __restrict__ c,
                              const float* __restrict__ sums,
                              const int* __restrict__ counts,
                              float* __restrict__ out_upd) {
    int i = blockIdx.x * blockDim.x + threadIdx.x;
    if (i < KCLUS * FEAT) {
        int   k   = i >> 6;
        float cv  = c[i];
        int   cnt = counts[k];
        float nc  = (cnt > 0) ? (sums[i] / (float)cnt) : cv;
        out_upd[i] = 0.99f * cv + 0.01f * nc;
    }
}

extern "C" void kernel_launch(void* const* d_in, const int* in_sizes, int n_in,
                              void* d_out, int out_size, void* d_ws, size_t ws_size,
                              hipStream_t stream) {
    const float* x = (const float*)d_in[0];
    const float* c = (const float*)d_in[1];

    float* out        = (float*)d_out;
    float* out_assign = out;           // [0, N): assignments as float
    float* out_upd    = out + NPTS;    // [N, N + K*FEAT)

    char*  ws     = (char*)d_ws;
    float* cnorm  = (float*)ws;                      // 8 KB   @ 0
    float* sums   = (float*)(ws + 8192);             // 512 KB @ 8192
    int*   counts = (int*)(ws + 8192 + 524288);      // 8 KB   @ 532480
    float* cmax   = (float*)(ws + 540672);           // 4 B    @ 540672 (16-pad)
    float* xn     = (float*)(ws + 540688);           // 512 KB @ 540688
    short* cbs    = (short*)(ws + 540688 + 524288);  // 256 KB @ 1064976 (16-aligned)

    // sums + counts + cmax contiguous: one async memset (graph-capture safe)
    hipMemsetAsync(ws + 8192, 0, 524288 + 8192 + 4, stream);

    cprep_kernel<<<KCLUS / 256, 256, 0, stream>>>(c, cnorm, cbs, cmax);
    xprep_kernel<<<NPTS / 256, 256, 0, stream>>>(x, xn);
    assign_kernel<<<NPTS / 256, 256, 0, stream>>>(x, c, cbs, cnorm, xn, cmax, out_assign);
    scatter_kernel<<<NPTS / 256, 256, 0, stream>>>(x, out_assign, sums, counts);
    update_kernel<<<(KCLUS * FEAT) / 256, 256, 0, stream>>>(c, sums, counts, out_upd);
}